// Round 5
// baseline (763.645 us; speedup 1.0000x reference)
//
#include <hip/hip_runtime.h>
#include <hip/hip_bf16.h>

// ---------------- common helpers ----------------
typedef unsigned short u16;
typedef unsigned int   u32;
typedef float  f32x4 __attribute__((ext_vector_type(4)));
typedef short  s16x8 __attribute__((ext_vector_type(8)));

__device__ __forceinline__ float bf2f(u16 u) {
    return __uint_as_float(((unsigned int)u) << 16);
}
__device__ __forceinline__ u16 f2bf(float f) {
    unsigned int x = __float_as_uint(f);
    unsigned int r = x + 0x7fffu + ((x >> 16) & 1u);
    return (u16)(r >> 16);
}

#define WIMG 128
#define HIMG 128
#define PADW 130
#define BIMG 8
#define CIN  64
#define NPOINT 128
#define NINST 512

// async global->LDS, 16B per lane, wave-uniform LDS base (HW places lane i at base+16*i)
#define AS1 __attribute__((address_space(1)))
#define AS3 __attribute__((address_space(3)))
__device__ __forceinline__ void async16(const void* g, void* l) {
    __builtin_amdgcn_global_load_lds((const AS1 void*)g, (AS3 void*)l, 16, 0, 0);
}

// counted-vmcnt pipeline primitives (T4: loads stay in flight across barriers)
#define SWAIT_VM4()   asm volatile("s_waitcnt vmcnt(4)" ::: "memory")
#define SWAIT_VM0()   asm volatile("s_waitcnt vmcnt(0)" ::: "memory")
#define SWAIT_LGKM0() asm volatile("s_waitcnt lgkmcnt(0)" ::: "memory")
#define SBAR()        __builtin_amdgcn_s_barrier()
#define SCHED0()      __builtin_amdgcn_sched_barrier(0)

// ---------------- weight conversion (f32 -> bf16, MFMA-friendly layouts) ----------------
// w1 (256 oc, 64 ic, 3, 3) -> wb1[oc][kp*64+ic], kp = ky*3+kx  (Bt layout: N=256 x K=576)
__global__ __launch_bounds__(256) void k_cvt_w1(const float* __restrict__ w,
                                                u16* __restrict__ wb) {
    int idx = blockIdx.x * 256 + threadIdx.x;   // 147456
    int oc = idx / 576, r = idx % 576;
    int kp = r >> 6, ic = r & 63;
    wb[idx] = f2bf(w[oc * 576 + ic * 9 + kp]);
}

// w2 (254 oc, 256 ic) -> wb2[oc][ic] bf16, rows oc>=254 zero  (Bt: 256 x 256)
__global__ __launch_bounds__(256) void k_cvt_w2(const float* __restrict__ w,
                                                u16* __restrict__ wb) {
    int idx = blockIdx.x * 256 + threadIdx.x;   // 65536
    int oc = idx >> 8, ic = idx & 255;
    wb[idx] = (oc < 254) ? f2bf(w[oc * 256 + ic]) : (u16)0;
}

// wqkv (256 k, 768 n) -> wqT[n][k] bf16  (Bt: 768 x 256)
__global__ __launch_bounds__(256) void k_cvt_wqkv(const float* __restrict__ w,
                                                  u16* __restrict__ wb) {
    int idx = blockIdx.x * 256 + threadIdx.x;   // 196608
    int n = idx >> 8, k = idx & 255;
    wb[idx] = f2bf(w[k * 768 + n]);
}

// W2 = wo @ whead (256x2), b2 = bo @ whead + bhead (2), all f32
__global__ __launch_bounds__(256) void k_headfuse(const float* __restrict__ wo,
                                                  const float* __restrict__ bo,
                                                  const float* __restrict__ whead,
                                                  const float* __restrict__ bhead,
                                                  float* __restrict__ W2,
                                                  float* __restrict__ b2) {
    int idx = blockIdx.x * 256 + threadIdx.x;   // 512 total
    if (idx < 512) {
        int c = idx >> 1, j = idx & 1;
        float s = 0.f;
        for (int t = 0; t < 256; ++t)
            s = fmaf(wo[c * 256 + t], whead[t * 2 + j], s);
        W2[idx] = s;
    }
    if (idx < 2) {
        float s = bhead[idx];
        for (int t = 0; t < 256; ++t)
            s = fmaf(bo[t], whead[t * 2 + idx], s);
        b2[idx] = s;
    }
}

// ---------------- zero ONLY the halo of the padded NHWC buffer ----------------
// halo = 516 px/image (y in {0,129} full rows, x in {0,129} cols), 8 uint4 per px.
__global__ __launch_bounds__(256) void k_halo(u16* __restrict__ p) {
    int idx = blockIdx.x * 256 + threadIdx.x;   // 8*516*8 = 33024 uint4
    if (idx >= 33024) return;
    int img = idx / 4128, r = idx % 4128;
    int h = r >> 3, c = r & 7;
    int x, y;
    if (h < 130)      { y = 0;   x = h; }
    else if (h < 260) { y = 129; x = h - 130; }
    else if (h < 388) { x = 0;   y = h - 259; }
    else              { x = 129; y = h - 387; }
    *(uint4*)&p[(((size_t)img * PADW + y) * PADW + x) * 64 + c * 8] =
        make_uint4(0u, 0u, 0u, 0u);
}

// ---------------- NCHW f32 (8,64,128,128) -> padded NHWC bf16 (8,130,130,64) ----------------
__global__ __launch_bounds__(256) void k_nhwc(const float* __restrict__ in,
                                              u16* __restrict__ out) {
    __shared__ u16 sT[128][80];   // [x][ic], stride 80 u16 = 160 B
    int b = blockIdx.x >> 7, y = blockIdx.x & 127;
    int tid = threadIdx.x;
    const float* ib = in + ((size_t)b * CIN * HIMG + y) * WIMG;
    int x4 = tid & 31, icg = tid >> 5;
    #pragma unroll
    for (int pass = 0; pass < 8; ++pass) {
        int ic = pass * 8 + icg;
        float4 v = *(const float4*)&ib[(size_t)ic * (HIMG * WIMG) + x4 * 4];
        sT[x4 * 4 + 0][ic] = f2bf(v.x);
        sT[x4 * 4 + 1][ic] = f2bf(v.y);
        sT[x4 * 4 + 2][ic] = f2bf(v.z);
        sT[x4 * 4 + 3][ic] = f2bf(v.w);
    }
    __syncthreads();
    u16* ob = out + ((size_t)(b * PADW + y + 1) * PADW + 1) * 64;
    int icu = tid & 7, xw = tid >> 3;
    #pragma unroll
    for (int pass = 0; pass < 4; ++pass) {
        int x = pass * 32 + xw;
        uint4 v = *(const uint4*)&sT[x][icu * 8];
        *(uint4*)&ob[(size_t)x * 64 + icu * 8] = v;
    }
}

// ---------------- init polys ----------------
__global__ __launch_bounds__(256) void k_init(const float* __restrict__ whp,
                                              const int* __restrict__ ct_ind,
                                              const int* __restrict__ ct_img,
                                              float* __restrict__ points1,
                                              float* __restrict__ out0) {
    int i = blockIdx.x;
    int t = threadIdx.x;              // t = 2*p + c
    int ind = ct_ind[i];
    int x = ind % WIMG, y = ind / WIMG;
    int b = ct_img[i];
    int p = t >> 1, c = t & 1;
    float off = whp[(((size_t)b * 2 * NPOINT + t) * HIMG + y) * WIMG + x];
    float ctc = (c == 0) ? (float)x : (float)y;
    float ip = off * 10.0f + ctc;
    points1[((size_t)i * 129 + 1 + p) * 2 + c] = ip;
    if (t < 2) points1[(size_t)i * 129 * 2 + t] = (t == 0) ? (float)x : (float)y;
    out0[((size_t)i * NPOINT + p) * 2 + c] = ip * 4.0f;
}

// ---------------- fused conv(3x3,64->256)+relu -> 1x1 (256ic->256oc) + bias ----------------
// Block = 64 px x 256 oc, 256 thr / 4 waves; wave tile 64x64 both phases.
// Counted-vmcnt pipeline (T4): stage loads stay in flight across both barriers; no
// vmcnt(0) drain in steady state. LDS 65 KB -> 2 blocks/CU.
__global__ __launch_bounds__(256, 2) void k_convgemm(const u16* __restrict__ inTp,
                                                     const u16* __restrict__ wb1,
                                                     const float* __restrict__ b1,
                                                     const u16* __restrict__ wb2,
                                                     const float* __restrict__ b2,
                                                     u16* __restrict__ feat) {
    // layout (u16): sB [2][8192] @0 (32KB) | sW [12672] @16384 (A window, phase1)
    //               sC [64][264] @16384 (16896, aliases sW for phase2). total 33280.
    __shared__ u16 smem[33280];
    u16* sB = smem;
    u16* sW = smem + 16384;
    u16* sC = smem + 16384;

    int tid = threadIdx.x;
    int wave = tid >> 6, lane = tid & 63;
    int quad = lane >> 4, l16 = lane & 15;
    int rl = lane >> 2, part = lane & 3;
    int partS = part ^ ((rl ^ (rl >> 2)) & 3);   // staging swizzle (global side)
    int quadS = quad ^ ((l16 ^ (l16 >> 2)) & 3); // read swizzle (LDS side)

    int bx = blockIdx.x;                 // 0..255 -> (xcd, half, yo) bijective
    int y = (bx & 7) * 16 + (bx >> 4);   // XCD-chunked rows
    int half = (bx >> 3) & 1;
    int xb = half * 64;                  // padded-x window base
    int b = blockIdx.z;
    const u16* inb = inTp + (size_t)b * PADW * PADW * 64;

    // ---- stage A window once: 3 conv rows x 66 px x 64 ic, swizzled chunk slots ----
    for (int idx = tid; idx < 1584; idx += 256) {
        int r = idx / 528, g = idx - r * 528;
        int pxw = g >> 3, c = g & 7;
        uint4 v = *(const uint4*)&inb[((size_t)(y + r) * PADW + xb + pxw) * 64 + c * 8];
        *(uint4*)&sW[((r * 66 + pxw) * 8 + (c ^ (pxw & 7))) * 8] = v;
    }

    // B1 tile: 256 oc x 32 k; 4 async16 per wave
    auto stageB1 = [&](u16* dst, int t) {
        int kp = t >> 1, ic0 = (t & 1) << 5;
        const u16* brow = wb1 + (size_t)kp * 64 + ic0 + partS * 8;
        #pragma unroll
        for (int j = 0; j < 4; ++j) {
            int rr = wave * 64 + j * 16;
            async16(brow + (size_t)(rr + rl) * 576, dst + rr * 32);
        }
    };
    // B2 tile: 256 oc x 32 k from wb2; 4 async16 per wave
    auto stageB2 = [&](u16* dst, int kk) {
        #pragma unroll
        for (int j = 0; j < 4; ++j) {
            int rr = wave * 64 + j * 16;
            async16(wb2 + (size_t)(rr + rl) * 256 + kk + partS * 8, dst + rr * 32);
        }
    };

    // ---- phase 1: 3x3 conv, K=576, 18 steps; wave tile 64px x 64oc ----
    f32x4 acc1[4][4];
    #pragma unroll
    for (int mt = 0; mt < 4; ++mt)
        #pragma unroll
        for (int nt = 0; nt < 4; ++nt)
            #pragma unroll
            for (int q = 0; q < 4; ++q) acc1[mt][nt][q] = 0.f;

    auto body1 = [&](int buf, int t) {
        int kp = t >> 1, cdb = (t & 1) << 2;
        int ky = kp / 3, kx = kp - ky * 3;
        s16x8 aF[4], bF[4];
        #pragma unroll
        for (int mt = 0; mt < 4; ++mt) {
            int pxw = kx + mt * 16 + l16;
            int cd = cdb + quad;
            aF[mt] = *(const s16x8*)&sW[((ky * 66 + pxw) * 8 + (cd ^ (pxw & 7))) * 8];
        }
        #pragma unroll
        for (int nt = 0; nt < 4; ++nt)
            bF[nt] = *(const s16x8*)&sB[buf * 8192 + (wave * 64 + nt * 16 + l16) * 32 + quadS * 8];
        #pragma unroll
        for (int mt = 0; mt < 4; ++mt)
            #pragma unroll
            for (int nt = 0; nt < 4; ++nt)
                acc1[mt][nt] = __builtin_amdgcn_mfma_f32_16x16x32_bf16(
                    aF[mt], bF[nt], acc1[mt][nt], 0, 0, 0);
    };

    stageB1(sB, 0);
    stageB1(sB + 8192, 1);
    SWAIT_LGKM0();                 // own sW ds_writes committed before barrier
    for (int t = 0; t < 18; ++t) {
        if (t < 17) { SWAIT_VM4(); } else { SWAIT_VM0(); }
        SBAR(); SCHED0();
        body1(t & 1, t);
        SCHED0(); SBAR();
        if (t < 16) stageB1(sB + (t & 1) * 8192, t + 2);
    }

    // ---- transition: bias+relu -> sC (aliases sW; all reads consumed pre-barrier) ----
    #pragma unroll
    for (int nt = 0; nt < 4; ++nt) {
        int col = wave * 64 + nt * 16 + l16;
        float bv = b1[col];
        #pragma unroll
        for (int mt = 0; mt < 4; ++mt) {
            #pragma unroll
            for (int r = 0; r < 4; ++r) {
                int row = mt * 16 + quad * 4 + r;
                sC[row * 264 + col] = f2bf(fmaxf(acc1[mt][nt][r] + bv, 0.f));
            }
        }
    }

    // ---- phase 2: 1x1 gemm, K=256, 8 steps; wave tile 64px x 64oc ----
    f32x4 acc2[4][4];
    #pragma unroll
    for (int mt = 0; mt < 4; ++mt)
        #pragma unroll
        for (int nt = 0; nt < 4; ++nt)
            #pragma unroll
            for (int q = 0; q < 4; ++q) acc2[mt][nt][q] = 0.f;

    auto body2 = [&](int buf, int ik) {
        s16x8 a2[4], bb[4];
        #pragma unroll
        for (int mt = 0; mt < 4; ++mt)
            a2[mt] = *(const s16x8*)&sC[(mt * 16 + l16) * 264 + ik * 32 + quad * 8];
        #pragma unroll
        for (int nt = 0; nt < 4; ++nt)
            bb[nt] = *(const s16x8*)&sB[buf * 8192 + (wave * 64 + nt * 16 + l16) * 32 + quadS * 8];
        #pragma unroll
        for (int mt = 0; mt < 4; ++mt)
            #pragma unroll
            for (int nt = 0; nt < 4; ++nt)
                acc2[mt][nt] = __builtin_amdgcn_mfma_f32_16x16x32_bf16(
                    a2[mt], bb[nt], acc2[mt][nt], 0, 0, 0);
    };

    stageB2(sB, 0);
    stageB2(sB + 8192, 32);
    SWAIT_LGKM0();                 // own sC ds_writes committed before barrier
    for (int ik = 0; ik < 8; ++ik) {
        if (ik < 7) { SWAIT_VM4(); } else { SWAIT_VM0(); }
        SBAR(); SCHED0();
        body2(ik & 1, ik);
        SCHED0(); SBAR();
        if (ik < 6) stageB2(sB + (ik & 1) * 8192, (ik + 2) * 32);
    }

    // ---- epilogue: bias (254) -> sC (dead), coalesced 32 KB contiguous store ----
    #pragma unroll
    for (int nt = 0; nt < 4; ++nt) {
        int col = wave * 64 + nt * 16 + l16;
        float bv = (col < 254) ? b2[col] : 0.f;
        #pragma unroll
        for (int mt = 0; mt < 4; ++mt) {
            #pragma unroll
            for (int r = 0; r < 4; ++r) {
                int row = mt * 16 + quad * 4 + r;
                sC[row * 264 + col] = f2bf(acc2[mt][nt][r] + bv);
            }
        }
    }
    __syncthreads();
    u16* outb = feat + ((size_t)b * (HIMG * WIMG) + (size_t)y * 128 + half * 64) * 256;
    #pragma unroll
    for (int it = 0; it < 8; ++it) {
        int idx = it * 256 + tid;
        int row = idx >> 5, ch = idx & 31;
        *(uint4*)&outb[(size_t)row * 256 + ch * 8] = *(const uint4*)&sC[row * 264 + ch * 8];
    }
}

// ---------------- MFMA NT GEMM: C(MxN bf16) = act(A(MxK bf16) @ Bt(NxK)^T + bias) --------
// Counted-vmcnt dbuf pipeline; XCD swizzle; LDS-coalesced epilogue aliased over sA/sB.
// LDS 32.8 KB -> 4 blocks/CU.
__global__ __launch_bounds__(256, 4) void k_gemm_mfma(const u16* __restrict__ A,
                                                      const u16* __restrict__ Bt,
                                                      const float* __restrict__ bias, int nbias,
                                                      u16* __restrict__ C,
                                                      int M, int N, int K, int relu) {
    __shared__ u16 smem[16384];          // sA [2][4096] @0 | sB [2][4096] @8192
    u16* sA = smem;                      // sOut [64][132] aliases @0 (epilogue only)
    u16* sB = smem + 8192;
    u16* sOut = smem;
    int tid = threadIdx.x;
    int wave = tid >> 6, lane = tid & 63;
    int quad = lane >> 4, l16 = lane & 15;
    int rl = lane >> 2, part = lane & 3;
    int partS = part ^ ((rl ^ (rl >> 2)) & 3);
    int quadS = quad ^ ((l16 ^ (l16 >> 2)) & 3);
    int r0 = wave * 32;

    // bijective XCD swizzle, n-fastest enumeration
    int gx = gridDim.x, gy = gridDim.y;
    int o = blockIdx.y * gx + blockIdx.x;
    int nwg = gx * gy;
    int qn = nwg >> 3, r8 = nwg & 7;
    int xcd = o & 7, oi = o >> 3;
    int vid = (xcd < r8) ? xcd * (qn + 1) + oi : r8 * (qn + 1) + (xcd - r8) * qn + oi;
    int m0 = (vid / gy) * 128, n0 = (vid % gy) * 128;
    int wm = (wave >> 1) * 64, wn = (wave & 1) * 64;

    f32x4 acc[4][4];
    #pragma unroll
    for (int a = 0; a < 4; ++a)
        #pragma unroll
        for (int b = 0; b < 4; ++b)
            #pragma unroll
            for (int q = 0; q < 4; ++q) acc[a][b][q] = 0.f;

    auto stage = [&](int bufi, int kk) {
        #pragma unroll
        for (int j = 0; j < 2; ++j) {
            int rr = r0 + j * 16;
            async16(&A[(size_t)(m0 + rr + rl) * K + kk + partS * 8], &sA[bufi * 4096 + rr * 32]);
            async16(&Bt[(size_t)(n0 + rr + rl) * K + kk + partS * 8], &sB[bufi * 4096 + rr * 32]);
        }
    };
    auto body = [&](int buf) {
        s16x8 aF[4], bF[4];
        #pragma unroll
        for (int mt = 0; mt < 4; ++mt)
            aF[mt] = *(const s16x8*)&sA[buf * 4096 + (wm + mt * 16 + l16) * 32 + quadS * 8];
        #pragma unroll
        for (int nt = 0; nt < 4; ++nt)
            bF[nt] = *(const s16x8*)&sB[buf * 4096 + (wn + nt * 16 + l16) * 32 + quadS * 8];
        #pragma unroll
        for (int mt = 0; mt < 4; ++mt)
            #pragma unroll
            for (int nt = 0; nt < 4; ++nt)
                acc[mt][nt] = __builtin_amdgcn_mfma_f32_16x16x32_bf16(
                    aF[mt], bF[nt], acc[mt][nt], 0, 0, 0);
    };

    int nk = K >> 5;
    stage(0, 0);
    stage(1, 32);
    for (int ik = 0; ik < nk; ++ik) {
        if (ik < nk - 1) { SWAIT_VM4(); } else { SWAIT_VM0(); }
        SBAR(); SCHED0();
        body(ik & 1);
        SCHED0(); SBAR();
        if (ik + 2 < nk) stage(ik & 1, (ik + 2) << 5);
    }

    // epilogue: two 64-row passes through sOut (aliases dead sA/sB), coalesced stores
    #pragma unroll
    for (int pass = 0; pass < 2; ++pass) {
        if ((wave >> 1) == pass) {
            #pragma unroll
            for (int nt = 0; nt < 4; ++nt) {
                int col = wn + nt * 16 + l16;
                int gcol = n0 + col;
                float bv = (gcol < nbias) ? bias[gcol] : 0.f;
                #pragma unroll
                for (int mt = 0; mt < 4; ++mt) {
                    #pragma unroll
                    for (int r = 0; r < 4; ++r) {
                        int rowl = mt * 16 + quad * 4 + r;
                        float v = acc[mt][nt][r] + bv;
                        if (relu) v = fmaxf(v, 0.f);
                        sOut[rowl * 132 + col] = f2bf(v);
                    }
                }
            }
        }
        __syncthreads();
        #pragma unroll
        for (int it = 0; it < 8; ++it) {
            int idx = it * 256 + tid;
            int rowl = idx >> 5, ch = idx & 31;
            *(uint2*)&C[(size_t)(m0 + pass * 64 + rowl) * N + n0 + ch * 4] =
                *(const uint2*)&sOut[rowl * 132 + ch * 4];
        }
        __syncthreads();
    }
}

// ---------------- normalize_poly -> x[...,254:256] (bf16) ----------------
__global__ __launch_bounds__(256) void k_norm(const float* __restrict__ pts,
                                              u16* __restrict__ xout, int P) {
    int i = blockIdx.x, t = threadIdx.x;
    __shared__ float sx[256], sy[256];
    float px = 0.f, py = 0.f;
    if (t < P) {
        px = pts[((size_t)i * P + t) * 2 + 0];
        py = pts[((size_t)i * P + t) * 2 + 1];
    }
    sx[t] = px; sy[t] = py;
    __syncthreads();
    for (int s = 128; s > 0; s >>= 1) {
        if (t < s) { sx[t] += sx[t + s]; sy[t] += sy[t + s]; }
        __syncthreads();
    }
    float mx = sx[0] / (float)P, my = sy[0] / (float)P;
    __syncthreads();
    float ax = 0.f;
    if (t < P) ax = fmaxf(fabsf(px - mx), fabsf(py - my));
    sx[t] = ax;
    __syncthreads();
    for (int s = 128; s > 0; s >>= 1) {
        if (t < s) sx[t] = fmaxf(sx[t], sx[t + s]);
        __syncthreads();
    }
    float scale = sx[0] + 1e-6f;
    if (t < P) {
        size_t base = ((size_t)i * P + t) * 256;
        xout[base + 254] = f2bf((px - mx) / scale);
        xout[base + 255] = f2bf((py - my) / scale);
    }
}

// ---------------- bilinear sample: 2 points/block, 2 channels/thread (u32) ----------------
__global__ __launch_bounds__(256) void k_sample(const u16* __restrict__ feat,
                                                const float* __restrict__ pts,
                                                const int* __restrict__ ct_img,
                                                u16* __restrict__ xout, int P) {
    int i = blockIdx.x;
    int p = blockIdx.y * 2 + (threadIdx.x >> 7);
    int c0 = (threadIdx.x & 127) * 2;
    if (p >= P || c0 >= 254) return;
    float px = pts[((size_t)i * P + p) * 2 + 0];
    float py = pts[((size_t)i * P + p) * 2 + 1];
    int b = ct_img[i];
    float ix = px - 0.5f, iy = py - 0.5f;
    float x0f = floorf(ix), y0f = floorf(iy);
    float wx = ix - x0f, wy = iy - y0f;
    int x0 = (int)x0f, y0 = (int)y0f;
    float a0 = 0.f, a1 = 0.f;
    #pragma unroll
    for (int dy = 0; dy < 2; ++dy) {
        #pragma unroll
        for (int dx = 0; dx < 2; ++dx) {
            int xx = x0 + dx, yy = y0 + dy;
            float w = (dx ? wx : 1.f - wx) * (dy ? wy : 1.f - wy);
            if (xx >= 0 && xx < WIMG && yy >= 0 && yy < HIMG) {
                u32 v = *(const u32*)&feat[(((size_t)b * HIMG + yy) * WIMG + xx) * 256 + c0];
                a0 = fmaf(w, bf2f((u16)(v & 0xffffu)), a0);
                a1 = fmaf(w, bf2f((u16)(v >> 16)), a1);
            }
        }
    }
    u32 st = (u32)f2bf(a0) | ((u32)f2bf(a1) << 16);
    *(u32*)&xout[((size_t)i * P + p) * 256 + c0] = st;
}

// ---------------- MFMA attention (S^T = K@Q^T, O^T = V^T@P^T; no transposes) ----------------
__global__ __launch_bounds__(256) void k_attn_mfma(const u16* __restrict__ qkv, // (512*P,768)
                                                   u16* __restrict__ obuf,      // rows, 256 cols
                                                   int P) {
    __shared__ u16 smem[144 * 40 * 2 + 32 * 168];
    u16* sQ = smem;                     // stride 40
    u16* sK = smem + 144 * 40;          // stride 40
    u16* sVT = smem + 2 * 144 * 40;     // stride 168

    int il = blockIdx.x, h = blockIdx.y;
    int tid = threadIdx.x;
    int wave = tid >> 6, lane = tid & 63;
    int quad = lane >> 4, l16 = lane & 15;

    {
        u32* z = (u32*)smem;
        for (int i = tid; i < (144 * 40 * 2 + 32 * 168) / 2; i += 256) z[i] = 0u;
    }
    __syncthreads();
    for (int idx = tid; idx < 129 * 16 && (idx >> 4) < P; idx += 256) {
        int row = idx >> 4, c2 = idx & 15;
        size_t gb = ((size_t)il * P + row) * 768 + h * 32 + c2 * 2;
        *(u32*)&sQ[row * 40 + c2 * 2] = *(const u32*)&qkv[gb];
        *(u32*)&sK[row * 40 + c2 * 2] = *(const u32*)&qkv[gb + 256];
        u32 v = *(const u32*)&qkv[gb + 512];
        int kin = row & 31;
        int pcol = (row & ~31) + ((kin >> 2) & 3) * 8 + (kin >> 4) * 4 + (kin & 3);
        int d0 = c2 * 2;
        sVT[d0 * 168 + pcol] = (u16)(v & 0xffffu);
        sVT[(d0 + 1) * 168 + pcol] = (u16)(v >> 16);
    }
    __syncthreads();

    const float scale = 0.17677669529663689f;
    for (int qt = wave; qt < 9; qt += 4) {
        s16x8 bq = *(const s16x8*)&sQ[(qt * 16 + l16) * 40 + quad * 8];
        f32x4 s4[9];
        #pragma unroll
        for (int kt = 0; kt < 9; ++kt) {
            s16x8 aK = *(const s16x8*)&sK[(kt * 16 + l16) * 40 + quad * 8];
            f32x4 zz = {0.f, 0.f, 0.f, 0.f};
            s4[kt] = __builtin_amdgcn_mfma_f32_16x16x32_bf16(aK, bq, zz, 0, 0, 0);
        }
        float mx = -1e30f;
        #pragma unroll
        for (int kt = 0; kt < 9; ++kt)
            #pragma unroll
            for (int r = 0; r < 4; ++r) {
                int k = kt * 16 + quad * 4 + r;
                float v = (k < P) ? s4[kt][r] * scale : -1e30f;
                s4[kt][r] = v;
                mx = fmaxf(mx, v);
            }
        mx = fmaxf(mx, __shfl_xor(mx, 16));
        mx = fmaxf(mx, __shfl_xor(mx, 32));
        float l = 0.f;
        #pragma unroll
        for (int kt = 0; kt < 9; ++kt)
            #pragma unroll
            for (int r = 0; r < 4; ++r) {
                float e = __expf(s4[kt][r] - mx);
                s4[kt][r] = e;
                l += e;
            }
        l += __shfl_xor(l, 16);
        l += __shfl_xor(l, 32);
        u16 pb[9][4];
        #pragma unroll
        for (int kt = 0; kt < 9; ++kt)
            #pragma unroll
            for (int r = 0; r < 4; ++r) pb[kt][r] = f2bf(s4[kt][r]);
        f32x4 o[2];
        #pragma unroll
        for (int mt = 0; mt < 2; ++mt)
            #pragma unroll
            for (int q = 0; q < 4; ++q) o[mt][q] = 0.f;
        #pragma unroll
        for (int t = 0; t < 5; ++t) {
            s16x8 bp;
            #pragma unroll
            for (int j = 0; j < 4; ++j) bp[j] = (short)pb[2 * t][j];
            #pragma unroll
            for (int j = 0; j < 4; ++j)
                bp[4 + j] = (2 * t + 1 < 9) ? (short)pb[2 * t + 1][j] : (short)0;
            #pragma unroll
            for (int mt = 0; mt < 2; ++mt) {
                s16x8 aV = *(const s16x8*)&sVT[(mt * 16 + l16) * 168 + t * 32 + quad * 8];
                o[mt] = __builtin_amdgcn_mfma_f32_16x16x32_bf16(aV, bp, o[mt], 0, 0, 0);
            }
        }
        int q = qt * 16 + l16;
        if (q < P) {
            float inv = 1.f / l;
            size_t ob = ((size_t)il * P + q) * 256 + h * 32;
            #pragma unroll
            for (int mt = 0; mt < 2; ++mt) {
                ushort4 st;
                st.x = f2bf(o[mt][0] * inv);
                st.y = f2bf(o[mt][1] * inv);
                st.z = f2bf(o[mt][2] * inv);
                st.w = f2bf(o[mt][3] * inv);
                *(ushort4*)&obuf[ob + mt * 16 + quad * 4] = st;
            }
        }
    }
}

// ---------------- head projection + poly update ----------------
__global__ __launch_bounds__(256) void k_head1(const u16* __restrict__ obuf,
                                               const float* __restrict__ W2,
                                               const float* __restrict__ b2,
                                               const float* __restrict__ pts1,
                                               float* __restrict__ coarse,
                                               float* __restrict__ out1) {
    int wave = threadIdx.x >> 6, lane = threadIdx.x & 63;
    int m = blockIdx.x * 4 + wave;
    const u16* orow = obuf + (size_t)m * 256;
    ushort4 u = *(const ushort4*)(orow + lane * 4);
    float4 w0 = *(const float4*)(W2 + lane * 8);
    float4 w1 = *(const float4*)(W2 + lane * 8 + 4);
    float c0 = bf2f(u.x), c1 = bf2f(u.y), c2 = bf2f(u.z), c3 = bf2f(u.w);
    float s0 = c0 * w0.x + c1 * w0.z + c2 * w1.x + c3 * w1.z;
    float s1 = c0 * w0.y + c1 * w0.w + c2 * w1.y + c3 * w1.w;
    for (int off = 32; off > 0; off >>= 1) {
        s0 += __shfl_down(s0, off);
        s1 += __shfl_down(s1, off);
    }
    if (lane == 0) {
        int i = m / 129, p = m % 129;
        if (p > 0) {
            float o0 = s0 + b2[0], o1 = s1 + b2[1];
            float i0 = pts1[(size_t)m * 2 + 0];
            float i1 = pts1[(size_t)m * 2 + 1];
            float cc0 = o0 * 4.f + i0, cc1 = o1 * 4.f + i1;
            size_t cm = (size_t)i * 128 + (p - 1);
            coarse[cm * 2 + 0] = cc0;
            coarse[cm * 2 + 1] = cc1;
            out1[cm * 2 + 0] = cc0 * 4.f;
            out1[cm * 2 + 1] = cc1 * 4.f;
        }
    }
}

__global__ __launch_bounds__(256) void k_head2(const u16* __restrict__ obuf,
                                               const float* __restrict__ W2,
                                               const float* __restrict__ b2,
                                               const float* __restrict__ coarse,
                                               float* __restrict__ out2) {
    int wave = threadIdx.x >> 6, lane = threadIdx.x & 63;
    int m = blockIdx.x * 4 + wave;
    const u16* orow = obuf + (size_t)m * 256;
    ushort4 u = *(const ushort4*)(orow + lane * 4);
    float4 w0 = *(const float4*)(W2 + lane * 8);
    float4 w1 = *(const float4*)(W2 + lane * 8 + 4);
    float c0 = bf2f(u.x), c1 = bf2f(u.y), c2 = bf2f(u.z), c3 = bf2f(u.w);
    float s0 = c0 * w0.x + c1 * w0.z + c2 * w1.x + c3 * w1.z;
    float s1 = c0 * w0.y + c1 * w0.w + c2 * w1.y + c3 * w1.w;
    for (int off = 32; off > 0; off >>= 1) {
        s0 += __shfl_down(s0, off);
        s1 += __shfl_down(s1, off);
    }
    if (lane == 0) {
        float f0 = s0 + b2[0] + coarse[(size_t)m * 2 + 0];
        float f1 = s1 + b2[1] + coarse[(size_t)m * 2 + 1];
        out2[(size_t)m * 2 + 0] = f0 * 4.f;
        out2[(size_t)m * 2 + 1] = f1 * 4.f;
    }
}

// ---------------- host ----------------
extern "C" void kernel_launch(void* const* d_in, const int* in_sizes, int n_in,
                              void* d_out, int out_size, void* d_ws, size_t ws_size,
                              hipStream_t stream) {
    const float* cnn     = (const float*)d_in[0];
    const float* whp     = (const float*)d_in[1];
    const int*   ct_ind  = (const int*)d_in[2];
    const int*   ct_img  = (const int*)d_in[3];
    const float* f1_w1   = (const float*)d_in[4];
    const float* f1_b1   = (const float*)d_in[5];
    const float* f1_w2   = (const float*)d_in[6];
    const float* f1_b2   = (const float*)d_in[7];
    const float* f2_w1   = (const float*)d_in[8];
    const float* f2_b1   = (const float*)d_in[9];
    const float* f2_w2   = (const float*)d_in[10];
    const float* f2_b2   = (const float*)d_in[11];
    const float* c1_wqkv = (const float*)d_in[12];
    const float* c1_bqkv = (const float*)d_in[13];
    const float* c1_wo   = (const float*)d_in[14];
    const float* c1_bo   = (const float*)d_in[15];
    const float* c1_wh   = (const float*)d_in[16];
    const float* c1_bh   = (const float*)d_in[17];
    const float* c2_wqkv = (const float*)d_in[18];
    const float* c2_bqkv = (const float*)d_in[19];
    const float* c2_wo   = (const float*)d_in[20];
    const float* c2_bo   = (const float*)d_in[21];
    const float* c2_wh   = (const float*)d_in[22];
    const float* c2_bh   = (const float*)d_in[23];

    // ws layout
    char* ws = (char*)d_ws;
    float* points1 = (float*)(ws + 0);                // 528384 B
    float* coarse  = (float*)(ws + 528384);           // 524288 B
    float* W2_1    = (float*)(ws + 1052672);
    float* b2_1    = (float*)(ws + 1054720);
    float* W2_2    = (float*)(ws + 1054976);
    float* b2_2    = (float*)(ws + 1057024);
    u16*   wb1a    = (u16*)(ws + 1057280);            // 294912 B
    u16*   wb1b    = (u16*)(ws + 1352192);
    u16*   wb2a    = (u16*)(ws + 1647104);            // 131072 B
    u16*   wb2b    = (u16*)(ws + 1778176);
    u16*   wqT1    = (u16*)(ws + 1909248);            // 393216 B
    u16*   wqT2    = (u16*)(ws + 2302464);
    u16*   inT     = (u16*)(ws + 2695680);            // padded 8*130*130*64 bf16 = 17305600 B
    u16*   feat    = (u16*)(ws + 20001280);           // 8*16384*256 bf16 = 67108864 B
    u16*   xbuf    = (u16*)(ws + 87110144);           // 66048*256 bf16 = 33816576 B
    u16*   qkv_all = (u16*)(ws + 120926720);          // 66048*768 bf16 = 101449728 B
    // end: 222376448 B

    float* out0 = (float*)d_out;
    float* out1 = out0 + 131072;
    float* out2 = out0 + 262144;

    // prep
    k_cvt_w1<<<576, 256, 0, stream>>>(f1_w1, wb1a);
    k_cvt_w1<<<576, 256, 0, stream>>>(f2_w1, wb1b);
    k_cvt_w2<<<256, 256, 0, stream>>>(f1_w2, wb2a);
    k_cvt_w2<<<256, 256, 0, stream>>>(f2_w2, wb2b);
    k_cvt_wqkv<<<768, 256, 0, stream>>>(c1_wqkv, wqT1);
    k_cvt_wqkv<<<768, 256, 0, stream>>>(c2_wqkv, wqT2);
    k_headfuse<<<2, 256, 0, stream>>>(c1_wo, c1_bo, c1_wh, c1_bh, W2_1, b2_1);
    k_headfuse<<<2, 256, 0, stream>>>(c2_wo, c2_bo, c2_wh, c2_bh, W2_2, b2_2);
    k_init<<<NINST, 256, 0, stream>>>(whp, ct_ind, ct_img, points1, out0);
    k_halo<<<130, 256, 0, stream>>>(inT);
    k_nhwc<<<1024, 256, 0, stream>>>(cnn, inT);

    // ---- stage 1 ----
    k_convgemm<<<dim3(256, 1, 8), 256, 0, stream>>>(inT, wb1a, f1_b1, wb2a, f1_b2, feat);
    k_norm<<<NINST, 256, 0, stream>>>(points1, xbuf, 129);
    k_sample<<<dim3(NINST, 65), 256, 0, stream>>>(feat, points1, ct_img, xbuf, 129);
    k_gemm_mfma<<<dim3(516, 6), 256, 0, stream>>>(xbuf, wqT1, c1_bqkv, 768, qkv_all,
                                                  66048, 768, 256, 0);
    k_attn_mfma<<<dim3(NINST, 8), 256, 0, stream>>>(qkv_all, xbuf, 129);
    k_head1<<<16512, 256, 0, stream>>>(xbuf, W2_1, b2_1, points1, coarse, out1);

    // ---- stage 2 ----
    k_convgemm<<<dim3(256, 1, 8), 256, 0, stream>>>(inT, wb1b, f2_b1, wb2b, f2_b2, feat);
    k_norm<<<NINST, 256, 0, stream>>>(coarse, xbuf, 128);
    k_sample<<<dim3(NINST, 64), 256, 0, stream>>>(feat, coarse, ct_img, xbuf, 128);
    k_gemm_mfma<<<dim3(512, 6), 256, 0, stream>>>(xbuf, wqT2, c2_bqkv, 768, qkv_all,
                                                  65536, 768, 256, 0);
    k_attn_mfma<<<dim3(NINST, 8), 256, 0, stream>>>(qkv_all, xbuf, 128);
    k_head2<<<16384, 256, 0, stream>>>(xbuf, W2_2, b2_2, coarse, out2);
}

// Round 7
// 689.349 us; speedup vs baseline: 1.1078x; 1.1078x over previous
//
#include <hip/hip_runtime.h>
#include <hip/hip_bf16.h>

// ---------------- common helpers ----------------
typedef unsigned short u16;
typedef unsigned int   u32;
typedef float  f32x4 __attribute__((ext_vector_type(4)));
typedef short  s16x8 __attribute__((ext_vector_type(8)));

__device__ __forceinline__ float bf2f(u16 u) {
    return __uint_as_float(((unsigned int)u) << 16);
}
__device__ __forceinline__ u16 f2bf(float f) {
    unsigned int x = __float_as_uint(f);
    unsigned int r = x + 0x7fffu + ((x >> 16) & 1u);
    return (u16)(r >> 16);
}

#define WIMG 128
#define HIMG 128
#define PADW 130
#define BIMG 8
#define CIN  64
#define NPOINT 128
#define NINST 512

// async global->LDS, 16B per lane, wave-uniform LDS base (HW places lane i at base+16*i)
#define AS1 __attribute__((address_space(1)))
#define AS3 __attribute__((address_space(3)))
__device__ __forceinline__ void async16(const void* g, void* l) {
    __builtin_amdgcn_global_load_lds((const AS1 void*)g, (AS3 void*)l, 16, 0, 0);
}

// counted-vmcnt pipeline primitives (verified r4/r5 structure)
#define SWAIT_VM4()   asm volatile("s_waitcnt vmcnt(4)" ::: "memory")
#define SWAIT_VM0()   asm volatile("s_waitcnt vmcnt(0)" ::: "memory")
#define SWAIT_LGKM0() asm volatile("s_waitcnt lgkmcnt(0)" ::: "memory")
#define SBAR()        __builtin_amdgcn_s_barrier()
#define SCHED0()      __builtin_amdgcn_sched_barrier(0)

// ---------------- fused prep: all weight conversions + headfuse + init + halo ----------------
// grid 3846 x 256. Ranges:
// [0,1152) cvt_w1 (a,b) | [1152,1664) cvt_w2 (a,b) | [1664,3200) cvt_wqkv (1,2)
// [3200,3204) headfuse (1,2) | [3204,3716) init | [3716,3846) halo
__global__ __launch_bounds__(256) void k_prep(
    const float* __restrict__ w1a, const float* __restrict__ w1b,
    const float* __restrict__ w2a_, const float* __restrict__ w2b_,
    const float* __restrict__ wqv1, const float* __restrict__ wqv2,
    const float* __restrict__ wo1, const float* __restrict__ bo1,
    const float* __restrict__ wh1, const float* __restrict__ bh1,
    const float* __restrict__ wo2, const float* __restrict__ bo2,
    const float* __restrict__ wh2, const float* __restrict__ bh2,
    const float* __restrict__ whp, const int* __restrict__ ct_ind,
    const int* __restrict__ ct_img,
    u16* __restrict__ wb1a, u16* __restrict__ wb1b,
    u16* __restrict__ wb2a, u16* __restrict__ wb2b,
    u16* __restrict__ wqT1, u16* __restrict__ wqT2,
    float* __restrict__ W2_1, float* __restrict__ b2_1,
    float* __restrict__ W2_2, float* __restrict__ b2_2,
    float* __restrict__ points1, float* __restrict__ out0,
    u16* __restrict__ inT)
{
    int bx = blockIdx.x, tid = threadIdx.x;
    if (bx < 1152) {
        // w1 (256 oc, 64 ic, 3, 3) -> [oc][kp*64+ic]
        const float* w = (bx < 576) ? w1a : w1b;
        u16* wb = (bx < 576) ? wb1a : wb1b;
        int idx = (bx % 576) * 256 + tid;
        int oc = idx / 576, r = idx % 576;
        int kp = r >> 6, ic = r & 63;
        wb[idx] = f2bf(w[oc * 576 + ic * 9 + kp]);
    } else if (bx < 1664) {
        // w2 (254 oc, 256 ic) -> [oc][ic], rows >=254 zero
        const float* w = (bx < 1408) ? w2a_ : w2b_;
        u16* wb = (bx < 1408) ? wb2a : wb2b;
        int idx = ((bx - 1152) & 255) * 256 + tid;
        int oc = idx >> 8, ic = idx & 255;
        wb[idx] = (oc < 254) ? f2bf(w[oc * 256 + ic]) : (u16)0;
    } else if (bx < 3200) {
        // wqkv (256 k, 768 n) -> [n][k]
        const float* w = (bx < 2432) ? wqv1 : wqv2;
        u16* wb = (bx < 2432) ? wqT1 : wqT2;
        int idx = ((bx - 1664) % 768) * 256 + tid;
        int n = idx >> 8, k = idx & 255;
        wb[idx] = f2bf(w[k * 768 + n]);
    } else if (bx < 3204) {
        int s = (bx - 3200) >> 1;
        const float* wo = s ? wo2 : wo1;
        const float* bo = s ? bo2 : bo1;
        const float* wh = s ? wh2 : wh1;
        const float* bh = s ? bh2 : bh1;
        float* W2 = s ? W2_2 : W2_1;
        float* b2 = s ? b2_2 : b2_1;
        int idx = ((bx - 3200) & 1) * 256 + tid;
        if (idx < 512) {
            int c = idx >> 1, j = idx & 1;
            float sm = 0.f;
            for (int t = 0; t < 256; ++t)
                sm = fmaf(wo[c * 256 + t], wh[t * 2 + j], sm);
            W2[idx] = sm;
        }
        if (idx < 2) {
            float sm = bh[idx];
            for (int t = 0; t < 256; ++t)
                sm = fmaf(bo[t], wh[t * 2 + idx], sm);
            b2[idx] = sm;
        }
    } else if (bx < 3716) {
        // init polys
        int i = bx - 3204;
        int t = tid;
        int ind = ct_ind[i];
        int x = ind % WIMG, y = ind / WIMG;
        int b = ct_img[i];
        int p = t >> 1, c = t & 1;
        float off = whp[(((size_t)b * 2 * NPOINT + t) * HIMG + y) * WIMG + x];
        float ctc = (c == 0) ? (float)x : (float)y;
        float ip = off * 10.0f + ctc;
        points1[((size_t)i * 129 + 1 + p) * 2 + c] = ip;
        if (t < 2) points1[(size_t)i * 129 * 2 + t] = (t == 0) ? (float)x : (float)y;
        out0[((size_t)i * NPOINT + p) * 2 + c] = ip * 4.0f;
    } else {
        // halo zero of padded NHWC: 8*516*8 = 33024 uint4
        int idx = (bx - 3716) * 256 + tid;
        if (idx < 33024) {
            int img = idx / 4128, r = idx % 4128;
            int h = r >> 3, c = r & 7;
            int x, y;
            if (h < 130)      { y = 0;   x = h; }
            else if (h < 260) { y = 129; x = h - 130; }
            else if (h < 388) { x = 0;   y = h - 259; }
            else              { x = 129; y = h - 387; }
            *(uint4*)&inT[(((size_t)img * PADW + y) * PADW + x) * 64 + c * 8] =
                make_uint4(0u, 0u, 0u, 0u);
        }
    }
}

// ---------------- NCHW f32 (8,64,128,128) -> padded NHWC bf16 (8,130,130,64) ----------------
__global__ __launch_bounds__(256) void k_nhwc(const float* __restrict__ in,
                                              u16* __restrict__ out) {
    __shared__ u16 sT[128][80];   // [x][ic], stride 80 u16 = 160 B
    int b = blockIdx.x >> 7, y = blockIdx.x & 127;
    int tid = threadIdx.x;
    const float* ib = in + ((size_t)b * CIN * HIMG + y) * WIMG;
    int x4 = tid & 31, icg = tid >> 5;
    #pragma unroll
    for (int pass = 0; pass < 8; ++pass) {
        int ic = pass * 8 + icg;
        float4 v = *(const float4*)&ib[(size_t)ic * (HIMG * WIMG) + x4 * 4];
        sT[x4 * 4 + 0][ic] = f2bf(v.x);
        sT[x4 * 4 + 1][ic] = f2bf(v.y);
        sT[x4 * 4 + 2][ic] = f2bf(v.z);
        sT[x4 * 4 + 3][ic] = f2bf(v.w);
    }
    __syncthreads();
    u16* ob = out + ((size_t)(b * PADW + y + 1) * PADW + 1) * 64;
    int icu = tid & 7, xw = tid >> 3;
    #pragma unroll
    for (int pass = 0; pass < 4; ++pass) {
        int x = pass * 32 + xw;
        uint4 v = *(const uint4*)&sT[x][icu * 8];
        *(uint4*)&ob[(size_t)x * 64 + icu * 8] = v;
    }
}

// ---------------- fused conv(3x3,64->256)+relu -> 1x1 (256ic->256oc) + bias ----------------
// VERIFIED r4/r5 structure: Block = 64 px x 256 oc, 256 thr / 4 waves; wave tile 64x64.
// Two-barrier counted-vmcnt dbuf. A-window staged once; sC aliases sW. LDS 65 KB.
__global__ __launch_bounds__(256, 2) void k_convgemm(const u16* __restrict__ inTp,
                                                     const u16* __restrict__ wb1,
                                                     const float* __restrict__ b1,
                                                     const u16* __restrict__ wb2,
                                                     const float* __restrict__ b2,
                                                     u16* __restrict__ feat) {
    // layout (u16): sB [2][8192] @0 (32KB) | sW [12672] @16384 (A window, phase1)
    //               sC [64][264] @16384 (16896, aliases sW for phase2). total 33280.
    __shared__ u16 smem[33280];
    u16* sB = smem;
    u16* sW = smem + 16384;
    u16* sC = smem + 16384;

    int tid = threadIdx.x;
    int wave = tid >> 6, lane = tid & 63;
    int quad = lane >> 4, l16 = lane & 15;
    int rl = lane >> 2, part = lane & 3;
    int partS = part ^ ((rl ^ (rl >> 2)) & 3);   // staging swizzle (global side)
    int quadS = quad ^ ((l16 ^ (l16 >> 2)) & 3); // read swizzle (LDS side)

    int bx = blockIdx.x;                 // 0..255 -> (xcd, half, yo) bijective
    int y = (bx & 7) * 16 + (bx >> 4);   // XCD-chunked rows
    int half = (bx >> 3) & 1;
    int xb = half * 64;                  // padded-x window base
    int b = blockIdx.z;
    const u16* inb = inTp + (size_t)b * PADW * PADW * 64;

    // ---- stage A window once: 3 conv rows x 66 px x 64 ic, swizzled chunk slots ----
    for (int idx = tid; idx < 1584; idx += 256) {
        int r = idx / 528, g = idx - r * 528;
        int pxw = g >> 3, c = g & 7;
        uint4 v = *(const uint4*)&inb[((size_t)(y + r) * PADW + xb + pxw) * 64 + c * 8];
        *(uint4*)&sW[((r * 66 + pxw) * 8 + (c ^ (pxw & 7))) * 8] = v;
    }

    // B1 tile: 256 oc x 32 k; 4 async16 per wave
    auto stageB1 = [&](u16* dst, int t) {
        int kp = t >> 1, ic0 = (t & 1) << 5;
        const u16* brow = wb1 + (size_t)kp * 64 + ic0 + partS * 8;
        #pragma unroll
        for (int j = 0; j < 4; ++j) {
            int rr = wave * 64 + j * 16;
            async16(brow + (size_t)(rr + rl) * 576, dst + rr * 32);
        }
    };
    // B2 tile: 256 oc x 32 k from wb2; 4 async16 per wave
    auto stageB2 = [&](u16* dst, int kk) {
        #pragma unroll
        for (int j = 0; j < 4; ++j) {
            int rr = wave * 64 + j * 16;
            async16(wb2 + (size_t)(rr + rl) * 256 + kk + partS * 8, dst + rr * 32);
        }
    };

    // ---- phase 1: 3x3 conv, K=576, 18 steps; wave tile 64px x 64oc ----
    f32x4 acc1[4][4];
    #pragma unroll
    for (int mt = 0; mt < 4; ++mt)
        #pragma unroll
        for (int nt = 0; nt < 4; ++nt)
            #pragma unroll
            for (int q = 0; q < 4; ++q) acc1[mt][nt][q] = 0.f;

    auto body1 = [&](int buf, int t) {
        int kp = t >> 1, cdb = (t & 1) << 2;
        int ky = kp / 3, kx = kp - ky * 3;
        s16x8 aF[4], bF[4];
        #pragma unroll
        for (int mt = 0; mt < 4; ++mt) {
            int pxw = kx + mt * 16 + l16;
            int cd = cdb + quad;
            aF[mt] = *(const s16x8*)&sW[((ky * 66 + pxw) * 8 + (cd ^ (pxw & 7))) * 8];
        }
        #pragma unroll
        for (int nt = 0; nt < 4; ++nt)
            bF[nt] = *(const s16x8*)&sB[buf * 8192 + (wave * 64 + nt * 16 + l16) * 32 + quadS * 8];
        #pragma unroll
        for (int mt = 0; mt < 4; ++mt)
            #pragma unroll
            for (int nt = 0; nt < 4; ++nt)
                acc1[mt][nt] = __builtin_amdgcn_mfma_f32_16x16x32_bf16(
                    aF[mt], bF[nt], acc1[mt][nt], 0, 0, 0);
    };

    stageB1(sB, 0);
    stageB1(sB + 8192, 1);
    SWAIT_LGKM0();                 // own sW ds_writes committed before barrier
    for (int t = 0; t < 18; ++t) {
        if (t < 17) { SWAIT_VM4(); } else { SWAIT_VM0(); }
        SBAR(); SCHED0();
        body1(t & 1, t);
        SCHED0(); SBAR();
        if (t < 16) stageB1(sB + (t & 1) * 8192, t + 2);
    }

    // ---- transition: bias+relu -> sC (aliases sW; all reads consumed pre-barrier) ----
    #pragma unroll
    for (int nt = 0; nt < 4; ++nt) {
        int col = wave * 64 + nt * 16 + l16;
        float bv = b1[col];
        #pragma unroll
        for (int mt = 0; mt < 4; ++mt) {
            #pragma unroll
            for (int r = 0; r < 4; ++r) {
                int row = mt * 16 + quad * 4 + r;
                sC[row * 264 + col] = f2bf(fmaxf(acc1[mt][nt][r] + bv, 0.f));
            }
        }
    }

    // ---- phase 2: 1x1 gemm, K=256, 8 steps; wave tile 64px x 64oc ----
    f32x4 acc2[4][4];
    #pragma unroll
    for (int mt = 0; mt < 4; ++mt)
        #pragma unroll
        for (int nt = 0; nt < 4; ++nt)
            #pragma unroll
            for (int q = 0; q < 4; ++q) acc2[mt][nt][q] = 0.f;

    auto body2 = [&](int buf, int ik) {
        s16x8 a2[4], bb[4];
        #pragma unroll
        for (int mt = 0; mt < 4; ++mt)
            a2[mt] = *(const s16x8*)&sC[(mt * 16 + l16) * 264 + ik * 32 + quad * 8];
        #pragma unroll
        for (int nt = 0; nt < 4; ++nt)
            bb[nt] = *(const s16x8*)&sB[buf * 8192 + (wave * 64 + nt * 16 + l16) * 32 + quadS * 8];
        #pragma unroll
        for (int mt = 0; mt < 4; ++mt)
            #pragma unroll
            for (int nt = 0; nt < 4; ++nt)
                acc2[mt][nt] = __builtin_amdgcn_mfma_f32_16x16x32_bf16(
                    a2[mt], bb[nt], acc2[mt][nt], 0, 0, 0);
    };

    stageB2(sB, 0);
    stageB2(sB + 8192, 32);
    SWAIT_LGKM0();                 // own sC ds_writes committed before barrier
    for (int ik = 0; ik < 8; ++ik) {
        if (ik < 7) { SWAIT_VM4(); } else { SWAIT_VM0(); }
        SBAR(); SCHED0();
        body2(ik & 1, ik);
        SCHED0(); SBAR();
        if (ik < 6) stageB2(sB + (ik & 1) * 8192, (ik + 2) * 32);
    }

    // ---- epilogue: bias (254) -> sC (dead), coalesced 32 KB contiguous store ----
    #pragma unroll
    for (int nt = 0; nt < 4; ++nt) {
        int col = wave * 64 + nt * 16 + l16;
        float bv = (col < 254) ? b2[col] : 0.f;
        #pragma unroll
        for (int mt = 0; mt < 4; ++mt) {
            #pragma unroll
            for (int r = 0; r < 4; ++r) {
                int row = mt * 16 + quad * 4 + r;
                sC[row * 264 + col] = f2bf(acc2[mt][nt][r] + bv);
            }
        }
    }
    __syncthreads();
    u16* outb = feat + ((size_t)b * (HIMG * WIMG) + (size_t)y * 128 + half * 64) * 256;
    #pragma unroll
    for (int it = 0; it < 8; ++it) {
        int idx = it * 256 + tid;
        int row = idx >> 5, ch = idx & 31;
        *(uint4*)&outb[(size_t)row * 256 + ch * 8] = *(const uint4*)&sC[row * 264 + ch * 8];
    }
}

// ---------------- MFMA NT GEMM: C(MxN bf16) = act(A(MxK bf16) @ Bt(NxK)^T + bias) --------
// VERIFIED r4/r5: counted-vmcnt dbuf pipeline; XCD swizzle; LDS epilogue. 32.8 KB LDS.
__global__ __launch_bounds__(256, 4) void k_gemm_mfma(const u16* __restrict__ A,
                                                      const u16* __restrict__ Bt,
                                                      const float* __restrict__ bias, int nbias,
                                                      u16* __restrict__ C,
                                                      int M, int N, int K, int relu) {
    __shared__ u16 smem[16384];          // sA [2][4096] @0 | sB [2][4096] @8192
    u16* sA = smem;                      // sOut [64][132] aliases @0 (epilogue only)
    u16* sB = smem + 8192;
    u16* sOut = smem;
    int tid = threadIdx.x;
    int wave = tid >> 6, lane = tid & 63;
    int quad = lane >> 4, l16 = lane & 15;
    int rl = lane >> 2, part = lane & 3;
    int partS = part ^ ((rl ^ (rl >> 2)) & 3);
    int quadS = quad ^ ((l16 ^ (l16 >> 2)) & 3);
    int r0 = wave * 32;

    // bijective XCD swizzle, n-fastest enumeration
    int gx = gridDim.x, gy = gridDim.y;
    int o = blockIdx.y * gx + blockIdx.x;
    int nwg = gx * gy;
    int qn = nwg >> 3, r8 = nwg & 7;
    int xcd = o & 7, oi = o >> 3;
    int vid = (xcd < r8) ? xcd * (qn + 1) + oi : r8 * (qn + 1) + (xcd - r8) * qn + oi;
    int m0 = (vid / gy) * 128, n0 = (vid % gy) * 128;
    int wm = (wave >> 1) * 64, wn = (wave & 1) * 64;

    f32x4 acc[4][4];
    #pragma unroll
    for (int a = 0; a < 4; ++a)
        #pragma unroll
        for (int b = 0; b < 4; ++b)
            #pragma unroll
            for (int q = 0; q < 4; ++q) acc[a][b][q] = 0.f;

    auto stage = [&](int bufi, int kk) {
        #pragma unroll
        for (int j = 0; j < 2; ++j) {
            int rr = r0 + j * 16;
            async16(&A[(size_t)(m0 + rr + rl) * K + kk + partS * 8], &sA[bufi * 4096 + rr * 32]);
            async16(&Bt[(size_t)(n0 + rr + rl) * K + kk + partS * 8], &sB[bufi * 4096 + rr * 32]);
        }
    };
    auto body = [&](int buf) {
        s16x8 aF[4], bF[4];
        #pragma unroll
        for (int mt = 0; mt < 4; ++mt)
            aF[mt] = *(const s16x8*)&sA[buf * 4096 + (wm + mt * 16 + l16) * 32 + quadS * 8];
        #pragma unroll
        for (int nt = 0; nt < 4; ++nt)
            bF[nt] = *(const s16x8*)&sB[buf * 4096 + (wn + nt * 16 + l16) * 32 + quadS * 8];
        #pragma unroll
        for (int mt = 0; mt < 4; ++mt)
            #pragma unroll
            for (int nt = 0; nt < 4; ++nt)
                acc[mt][nt] = __builtin_amdgcn_mfma_f32_16x16x32_bf16(
                    aF[mt], bF[nt], acc[mt][nt], 0, 0, 0);
    };

    int nk = K >> 5;
    stage(0, 0);
    stage(1, 32);
    for (int ik = 0; ik < nk; ++ik) {
        if (ik < nk - 1) { SWAIT_VM4(); } else { SWAIT_VM0(); }
        SBAR(); SCHED0();
        body(ik & 1);
        SCHED0(); SBAR();
        if (ik + 2 < nk) stage(ik & 1, (ik + 2) << 5);
    }

    // epilogue: two 64-row passes through sOut (aliases dead sA/sB), coalesced stores
    #pragma unroll
    for (int pass = 0; pass < 2; ++pass) {
        if ((wave >> 1) == pass) {
            #pragma unroll
            for (int nt = 0; nt < 4; ++nt) {
                int col = wn + nt * 16 + l16;
                int gcol = n0 + col;
                float bv = (gcol < nbias) ? bias[gcol] : 0.f;
                #pragma unroll
                for (int mt = 0; mt < 4; ++mt) {
                    #pragma unroll
                    for (int r = 0; r < 4; ++r) {
                        int rowl = mt * 16 + quad * 4 + r;
                        float v = acc[mt][nt][r] + bv;
                        if (relu) v = fmaxf(v, 0.f);
                        sOut[rowl * 132 + col] = f2bf(v);
                    }
                }
            }
        }
        __syncthreads();
        #pragma unroll
        for (int it = 0; it < 8; ++it) {
            int idx = it * 256 + tid;
            int rowl = idx >> 5, ch = idx & 31;
            *(uint2*)&C[(size_t)(m0 + pass * 64 + rowl) * N + n0 + ch * 4] =
                *(const uint2*)&sOut[rowl * 132 + ch * 4];
        }
        __syncthreads();
    }
}

// ---------------- fused bilinear sample + normalize_poly ----------------
// blockIdx.y < normy: sample 2 points/block, 2 channels/thread (cols 0..253)
// blockIdx.y == normy: normalize_poly -> cols 254..255
__global__ __launch_bounds__(256) void k_sample(const u16* __restrict__ feat,
                                                const float* __restrict__ pts,
                                                const int* __restrict__ ct_img,
                                                u16* __restrict__ xout, int P, int normy) {
    int i = blockIdx.x;
    if ((int)blockIdx.y == normy) {
        // ---- normalize_poly ----
        int t = threadIdx.x;
        __shared__ float sx[256], sy[256];
        float px = 0.f, py = 0.f;
        if (t < P) {
            px = pts[((size_t)i * P + t) * 2 + 0];
            py = pts[((size_t)i * P + t) * 2 + 1];
        }
        sx[t] = px; sy[t] = py;
        __syncthreads();
        for (int s = 128; s > 0; s >>= 1) {
            if (t < s) { sx[t] += sx[t + s]; sy[t] += sy[t + s]; }
            __syncthreads();
        }
        float mx = sx[0] / (float)P, my = sy[0] / (float)P;
        __syncthreads();
        float ax = 0.f;
        if (t < P) ax = fmaxf(fabsf(px - mx), fabsf(py - my));
        sx[t] = ax;
        __syncthreads();
        for (int s = 128; s > 0; s >>= 1) {
            if (t < s) sx[t] = fmaxf(sx[t], sx[t + s]);
            __syncthreads();
        }
        float scale = sx[0] + 1e-6f;
        if (t < P) {
            size_t base = ((size_t)i * P + t) * 256;
            xout[base + 254] = f2bf((px - mx) / scale);
            xout[base + 255] = f2bf((py - my) / scale);
        }
        return;
    }
    // ---- bilinear sample ----
    int p = blockIdx.y * 2 + (threadIdx.x >> 7);
    int c0 = (threadIdx.x & 127) * 2;
    if (p >= P || c0 >= 254) return;
    float px = pts[((size_t)i * P + p) * 2 + 0];
    float py = pts[((size_t)i * P + p) * 2 + 1];
    int b = ct_img[i];
    float ix = px - 0.5f, iy = py - 0.5f;
    float x0f = floorf(ix), y0f = floorf(iy);
    float wx = ix - x0f, wy = iy - y0f;
    int x0 = (int)x0f, y0 = (int)y0f;
    float a0 = 0.f, a1 = 0.f;
    #pragma unroll
    for (int dy = 0; dy < 2; ++dy) {
        #pragma unroll
        for (int dx = 0; dx < 2; ++dx) {
            int xx = x0 + dx, yy = y0 + dy;
            float w = (dx ? wx : 1.f - wx) * (dy ? wy : 1.f - wy);
            if (xx >= 0 && xx < WIMG && yy >= 0 && yy < HIMG) {
                u32 v = *(const u32*)&feat[(((size_t)b * HIMG + yy) * WIMG + xx) * 256 + c0];
                a0 = fmaf(w, bf2f((u16)(v & 0xffffu)), a0);
                a1 = fmaf(w, bf2f((u16)(v >> 16)), a1);
            }
        }
    }
    u32 st = (u32)f2bf(a0) | ((u32)f2bf(a1) << 16);
    *(u32*)&xout[((size_t)i * P + p) * 256 + c0] = st;
}

// ---------------- MFMA attention (S^T = K@Q^T, O^T = V^T@P^T; no transposes) ----------------
__global__ __launch_bounds__(256) void k_attn_mfma(const u16* __restrict__ qkv, // (512*P,768)
                                                   u16* __restrict__ obuf,      // rows, 256 cols
                                                   int P) {
    __shared__ u16 smem[144 * 40 * 2 + 32 * 168];
    u16* sQ = smem;                     // stride 40
    u16* sK = smem + 144 * 40;          // stride 40
    u16* sVT = smem + 2 * 144 * 40;     // stride 168

    int il = blockIdx.x, h = blockIdx.y;
    int tid = threadIdx.x;
    int wave = tid >> 6, lane = tid & 63;
    int quad = lane >> 4, l16 = lane & 15;

    {
        u32* z = (u32*)smem;
        for (int i = tid; i < (144 * 40 * 2 + 32 * 168) / 2; i += 256) z[i] = 0u;
    }
    __syncthreads();
    for (int idx = tid; idx < 129 * 16 && (idx >> 4) < P; idx += 256) {
        int row = idx >> 4, c2 = idx & 15;
        size_t gb = ((size_t)il * P + row) * 768 + h * 32 + c2 * 2;
        *(u32*)&sQ[row * 40 + c2 * 2] = *(const u32*)&qkv[gb];
        *(u32*)&sK[row * 40 + c2 * 2] = *(const u32*)&qkv[gb + 256];
        u32 v = *(const u32*)&qkv[gb + 512];
        int kin = row & 31;
        int pcol = (row & ~31) + ((kin >> 2) & 3) * 8 + (kin >> 4) * 4 + (kin & 3);
        int d0 = c2 * 2;
        sVT[d0 * 168 + pcol] = (u16)(v & 0xffffu);
        sVT[(d0 + 1) * 168 + pcol] = (u16)(v >> 16);
    }
    __syncthreads();

    const float scale = 0.17677669529663689f;
    for (int qt = wave; qt < 9; qt += 4) {
        s16x8 bq = *(const s16x8*)&sQ[(qt * 16 + l16) * 40 + quad * 8];
        f32x4 s4[9];
        #pragma unroll
        for (int kt = 0; kt < 9; ++kt) {
            s16x8 aK = *(const s16x8*)&sK[(kt * 16 + l16) * 40 + quad * 8];
            f32x4 zz = {0.f, 0.f, 0.f, 0.f};
            s4[kt] = __builtin_amdgcn_mfma_f32_16x16x32_bf16(aK, bq, zz, 0, 0, 0);
        }
        float mx = -1e30f;
        #pragma unroll
        for (int kt = 0; kt < 9; ++kt)
            #pragma unroll
            for (int r = 0; r < 4; ++r) {
                int k = kt * 16 + quad * 4 + r;
                float v = (k < P) ? s4[kt][r] * scale : -1e30f;
                s4[kt][r] = v;
                mx = fmaxf(mx, v);
            }
        mx = fmaxf(mx, __shfl_xor(mx, 16));
        mx = fmaxf(mx, __shfl_xor(mx, 32));
        float l = 0.f;
        #pragma unroll
        for (int kt = 0; kt < 9; ++kt)
            #pragma unroll
            for (int r = 0; r < 4; ++r) {
                float e = __expf(s4[kt][r] - mx);
                s4[kt][r] = e;
                l += e;
            }
        l += __shfl_xor(l, 16);
        l += __shfl_xor(l, 32);
        u16 pb[9][4];
        #pragma unroll
        for (int kt = 0; kt < 9; ++kt)
            #pragma unroll
            for (int r = 0; r < 4; ++r) pb[kt][r] = f2bf(s4[kt][r]);
        f32x4 o[2];
        #pragma unroll
        for (int mt = 0; mt < 2; ++mt)
            #pragma unroll
            for (int q = 0; q < 4; ++q) o[mt][q] = 0.f;
        #pragma unroll
        for (int t = 0; t < 5; ++t) {
            s16x8 bp;
            #pragma unroll
            for (int j = 0; j < 4; ++j) bp[j] = (short)pb[2 * t][j];
            #pragma unroll
            for (int j = 0; j < 4; ++j)
                bp[4 + j] = (2 * t + 1 < 9) ? (short)pb[2 * t + 1][j] : (short)0;
            #pragma unroll
            for (int mt = 0; mt < 2; ++mt) {
                s16x8 aV = *(const s16x8*)&sVT[(mt * 16 + l16) * 168 + t * 32 + quad * 8];
                o[mt] = __builtin_amdgcn_mfma_f32_16x16x32_bf16(aV, bp, o[mt], 0, 0, 0);
            }
        }
        int q = qt * 16 + l16;
        if (q < P) {
            float inv = 1.f / l;
            size_t ob = ((size_t)il * P + q) * 256 + h * 32;
            #pragma unroll
            for (int mt = 0; mt < 2; ++mt) {
                ushort4 st;
                st.x = f2bf(o[mt][0] * inv);
                st.y = f2bf(o[mt][1] * inv);
                st.z = f2bf(o[mt][2] * inv);
                st.w = f2bf(o[mt][3] * inv);
                *(ushort4*)&obuf[ob + mt * 16 + quad * 4] = st;
            }
        }
    }
}

// ---------------- head projection + poly update ----------------
__global__ __launch_bounds__(256) void k_head1(const u16* __restrict__ obuf,
                                               const float* __restrict__ W2,
                                               const float* __restrict__ b2,
                                               const float* __restrict__ pts1,
                                               float* __restrict__ coarse,
                                               float* __restrict__ out1) {
    int wave = threadIdx.x >> 6, lane = threadIdx.x & 63;
    int m = blockIdx.x * 4 + wave;
    const u16* orow = obuf + (size_t)m * 256;
    ushort4 u = *(const ushort4*)(orow + lane * 4);
    float4 w0 = *(const float4*)(W2 + lane * 8);
    float4 w1 = *(const float4*)(W2 + lane * 8 + 4);
    float c0 = bf2f(u.x), c1 = bf2f(u.y), c2 = bf2f(u.z), c3 = bf2f(u.w);
    float s0 = c0 * w0.x + c1 * w0.z + c2 * w1.x + c3 * w1.z;
    float s1 = c0 * w0.y + c1 * w0.w + c2 * w1.y + c3 * w1.w;
    for (int off = 32; off > 0; off >>= 1) {
        s0 += __shfl_down(s0, off);
        s1 += __shfl_down(s1, off);
    }
    if (lane == 0) {
        int i = m / 129, p = m % 129;
        if (p > 0) {
            float o0 = s0 + b2[0], o1 = s1 + b2[1];
            float i0 = pts1[(size_t)m * 2 + 0];
            float i1 = pts1[(size_t)m * 2 + 1];
            float cc0 = o0 * 4.f + i0, cc1 = o1 * 4.f + i1;
            size_t cm = (size_t)i * 128 + (p - 1);
            coarse[cm * 2 + 0] = cc0;
            coarse[cm * 2 + 1] = cc1;
            out1[cm * 2 + 0] = cc0 * 4.f;
            out1[cm * 2 + 1] = cc1 * 4.f;
        }
    }
}

__global__ __launch_bounds__(256) void k_head2(const u16* __restrict__ obuf,
                                               const float* __restrict__ W2,
                                               const float* __restrict__ b2,
                                               const float* __restrict__ coarse,
                                               float* __restrict__ out2) {
    int wave = threadIdx.x >> 6, lane = threadIdx.x & 63;
    int m = blockIdx.x * 4 + wave;
    const u16* orow = obuf + (size_t)m * 256;
    ushort4 u = *(const ushort4*)(orow + lane * 4);
    float4 w0 = *(const float4*)(W2 + lane * 8);
    float4 w1 = *(const float4*)(W2 + lane * 8 + 4);
    float c0 = bf2f(u.x), c1 = bf2f(u.y), c2 = bf2f(u.z), c3 = bf2f(u.w);
    float s0 = c0 * w0.x + c1 * w0.z + c2 * w1.x + c3 * w1.z;
    float s1 = c0 * w0.y + c1 * w0.w + c2 * w1.y + c3 * w1.w;
    for (int off = 32; off > 0; off >>= 1) {
        s0 += __shfl_down(s0, off);
        s1 += __shfl_down(s1, off);
    }
    if (lane == 0) {
        float f0 = s0 + b2[0] + coarse[(size_t)m * 2 + 0];
        float f1 = s1 + b2[1] + coarse[(size_t)m * 2 + 1];
        out2[(size_t)m * 2 + 0] = f0 * 4.f;
        out2[(size_t)m * 2 + 1] = f1 * 4.f;
    }
}

// ---------------- host ----------------
extern "C" void kernel_launch(void* const* d_in, const int* in_sizes, int n_in,
                              void* d_out, int out_size, void* d_ws, size_t ws_size,
                              hipStream_t stream) {
    const float* cnn     = (const float*)d_in[0];
    const float* whp     = (const float*)d_in[1];
    const int*   ct_ind  = (const int*)d_in[2];
    const int*   ct_img  = (const int*)d_in[3];
    const float* f1_w1   = (const float*)d_in[4];
    const float* f1_b1   = (const float*)d_in[5];
    const float* f1_w2   = (const float*)d_in[6];
    const float* f1_b2   = (const float*)d_in[7];
    const float* f2_w1   = (const float*)d_in[8];
    const float* f2_b1   = (const float*)d_in[9];
    const float* f2_w2   = (const float*)d_in[10];
    const float* f2_b2   = (const float*)d_in[11];
    const float* c1_wqkv = (const float*)d_in[12];
    const float* c1_bqkv = (const float*)d_in[13];
    const float* c1_wo   = (const float*)d_in[14];
    const float* c1_bo   = (const float*)d_in[15];
    const float* c1_wh   = (const float*)d_in[16];
    const float* c1_bh   = (const float*)d_in[17];
    const float* c2_wqkv = (const float*)d_in[18];
    const float* c2_bqkv = (const float*)d_in[19];
    const float* c2_wo   = (const float*)d_in[20];
    const float* c2_bo   = (const float*)d_in[21];
    const float* c2_wh   = (const float*)d_in[22];
    const float* c2_bh   = (const float*)d_in[23];

    // ws layout
    char* ws = (char*)d_ws;
    float* points1 = (float*)(ws + 0);                // 528384 B
    float* coarse  = (float*)(ws + 528384);           // 524288 B
    float* W2_1    = (float*)(ws + 1052672);
    float* b2_1    = (float*)(ws + 1054720);
    float* W2_2    = (float*)(ws + 1054976);
    float* b2_2    = (float*)(ws + 1057024);
    u16*   wb1a    = (u16*)(ws + 1057280);            // 294912 B
    u16*   wb1b    = (u16*)(ws + 1352192);
    u16*   wb2a    = (u16*)(ws + 1647104);            // 131072 B
    u16*   wb2b    = (u16*)(ws + 1778176);
    u16*   wqT1    = (u16*)(ws + 1909248);            // 393216 B
    u16*   wqT2    = (u16*)(ws + 2302464);
    u16*   inT     = (u16*)(ws + 2695680);            // padded 8*130*130*64 bf16 = 17305600 B
    u16*   feat    = (u16*)(ws + 20001280);           // 8*16384*256 bf16 = 67108864 B
    u16*   xbuf    = (u16*)(ws + 87110144);           // 66048*256 bf16 = 33816576 B
    u16*   qkv_all = (u16*)(ws + 120926720);          // 66048*768 bf16 = 101449728 B
    // end: 222376448 B

    float* out0 = (float*)d_out;
    float* out1 = out0 + 131072;
    float* out2 = out0 + 262144;

    // prep (single fused dispatch) + NHWC transpose
    k_prep<<<3846, 256, 0, stream>>>(f1_w1, f2_w1, f1_w2, f2_w2, c1_wqkv, c2_wqkv,
                                     c1_wo, c1_bo, c1_wh, c1_bh,
                                     c2_wo, c2_bo, c2_wh, c2_bh,
                                     whp, ct_ind, ct_img,
                                     wb1a, wb1b, wb2a, wb2b, wqT1, wqT2,
                                     W2_1, b2_1, W2_2, b2_2, points1, out0, inT);
    k_nhwc<<<1024, 256, 0, stream>>>(cnn, inT);

    // ---- stage 1 ----
    k_convgemm<<<dim3(256, 1, 8), 256, 0, stream>>>(inT, wb1a, f1_b1, wb2a, f1_b2, feat);
    k_sample<<<dim3(NINST, 66), 256, 0, stream>>>(feat, points1, ct_img, xbuf, 129, 65);
    k_gemm_mfma<<<dim3(516, 6), 256, 0, stream>>>(xbuf, wqT1, c1_bqkv, 768, qkv_all,
                                                  66048, 768, 256, 0);
    k_attn_mfma<<<dim3(NINST, 8), 256, 0, stream>>>(qkv_all, xbuf, 129);
    k_head1<<<16512, 256, 0, stream>>>(xbuf, W2_1, b2_1, points1, coarse, out1);

    // ---- stage 2 ----
    k_convgemm<<<dim3(256, 1, 8), 256, 0, stream>>>(inT, wb1b, f2_b1, wb2b, f2_b2, feat);
    k_sample<<<dim3(NINST, 65), 256, 0, stream>>>(feat, coarse, ct_img, xbuf, 128, 64);
    k_gemm_mfma<<<dim3(512, 6), 256, 0, stream>>>(xbuf, wqT2, c2_bqkv, 768, qkv_all,
                                                  65536, 768, 256, 0);
    k_attn_mfma<<<dim3(NINST, 8), 256, 0, stream>>>(qkv_all, xbuf, 128);
    k_head2<<<16384, 256, 0, stream>>>(xbuf, W2_2, b2_2, coarse, out2);
}